// Round 6
// baseline (224.597 us; speedup 1.0000x reference)
//
#include <hip/hip_runtime.h>
#include <hip/hip_bf16.h>

#define DEV __device__ __forceinline__

typedef __attribute__((ext_vector_type(4))) float f32x4;
typedef __attribute__((ext_vector_type(8))) short s16x8;
typedef __attribute__((ext_vector_type(4))) unsigned u32x4;

constexpr int B_ = 4, N_ = 4096, D_ = 1024;

DEV float elu1f(float x) { return x > 0.f ? x + 1.f : __expf(x); }
DEV unsigned short f2bf(float x) {            // RNE fp32 -> bf16 (software; matches HW RNE)
  unsigned u = __float_as_uint(x);
  return (unsigned short)((u + 0x7fffu + ((u >> 16) & 1u)) >> 16);
}
DEV float bf2f(unsigned short h) { return __uint_as_float(((unsigned)h) << 16); }
DEV unsigned pack_bf2(float x, float y) {     // HW v_cvt RNE pair -> packed dword
  __hip_bfloat16 ha = __float2bfloat16(x), hb = __float2bfloat16(y);
  return (unsigned)__builtin_bit_cast(unsigned short, ha) |
         ((unsigned)__builtin_bit_cast(unsigned short, hb) << 16);
}

// ---------------- prep q: elu+1 -> bf16, linear ----------------
__global__ __launch_bounds__(256) void k_prep_q(const float* __restrict__ src,
                                                unsigned short* __restrict__ dst) {
  int n = B_ * N_ * D_ / 4;
  int stride = gridDim.x * blockDim.x;
  for (int i = blockIdx.x * blockDim.x + threadIdx.x; i < n; i += stride) {
    f32x4 x = ((const f32x4*)src)[i];
    unsigned long long r =
        (unsigned long long)((unsigned)f2bf(elu1f(x[0])) | ((unsigned)f2bf(elu1f(x[1])) << 16)) |
        ((unsigned long long)((unsigned)f2bf(elu1f(x[2])) | ((unsigned)f2bf(elu1f(x[3])) << 16)) << 32);
    ((unsigned long long*)dst)[i] = r;
  }
}

// ---------------- ksum2: combine the four kc-quarter partials ----------------
__global__ __launch_bounds__(256) void k_ksum2(const float* __restrict__ ksp, float* __restrict__ ksum) {
  int idx = blockIdx.x * 256 + threadIdx.x;    // 4096 = b*1024 + d
  int b = idx >> 10, d = idx & 1023;
  float a = 0.f;
  #pragma unroll
  for (int kc = 0; kc < 4; ++kc) a += ksp[(size_t)(kc * 4 + b) * 1024 + d];
  ksum[idx] = a;
}

// ---------------- denom[b,n] = sum_d q'_bf16 * ksum ----------------
__global__ __launch_bounds__(256) void k_denom(const unsigned short* __restrict__ qp,
                                               const float* __restrict__ ksum, float* __restrict__ den) {
  int wid = threadIdx.x >> 6, lane = threadIdx.x & 63;
  int row = blockIdx.x * 4 + wid;              // [0, B*N)
  int b = row >> 12;
  const unsigned short* qr = qp + (size_t)row * D_ + lane * 16;
  const float* ks = ksum + b * D_ + lane * 16;
  s16x8 h0 = *(const s16x8*)qr;
  s16x8 h1 = *(const s16x8*)(qr + 8);
  float acc = 0.f;
  #pragma unroll
  for (int j = 0; j < 8; ++j) acc += bf2f((unsigned short)h0[j]) * ks[j];
  #pragma unroll
  for (int j = 0; j < 8; ++j) acc += bf2f((unsigned short)h1[j]) * ks[8 + j];
  #pragma unroll
  for (int o = 32; o; o >>= 1) acc += __shfl_down(acc, o, 64);
  if (!lane) den[row] = acc;
}

// ---------------- shared GEMM machinery (used by gemm2): glds staging + XOR swizzle ----------------
DEV void stage8(const unsigned short* __restrict__ A, const unsigned short* __restrict__ Bp,
                long sA, long sB, unsigned short* LA, unsigned short* LB, int t, int kofs) {
  #pragma unroll
  for (int j = 0; j < 4; ++j) {
    int q = j * 256 + t;
    int r = q >> 3;
    int c = (q & 7) ^ (r & 7);
    const unsigned short* g = A + (size_t)r * sA + kofs + c * 8;
    unsigned short* l = LA + (q & ~63) * 8;    // wave-uniform base; HW adds lane*16
    __builtin_amdgcn_global_load_lds((const __attribute__((address_space(1))) unsigned int*)(const void*)g,
                                     (__attribute__((address_space(3))) unsigned int*)(void*)l, 16, 0, 0);
  }
  #pragma unroll
  for (int j = 0; j < 4; ++j) {
    int q = j * 256 + t;
    int r = q >> 3;
    int c = (q & 7) ^ (r & 7);
    const unsigned short* g = Bp + (size_t)r * sB + kofs + c * 8;
    unsigned short* l = LB + (q & ~63) * 8;
    __builtin_amdgcn_global_load_lds((const __attribute__((address_space(1))) unsigned int*)(const void*)g,
                                     (__attribute__((address_space(3))) unsigned int*)(void*)l, 16, 0, 0);
  }
}

DEV void mac128(const unsigned short* LA, const unsigned short* LB, int lane, int wm, int wn,
                f32x4 (&acc)[4][4]) {
  int rr = lane & 15, cq = lane >> 4;
  #pragma unroll
  for (int ks = 0; ks < 2; ++ks) {
    s16x8 af[4], bf[4];
    #pragma unroll
    for (int m = 0; m < 4; ++m) {
      int row = wm * 64 + m * 16 + rr;
      af[m] = *(const s16x8*)&LA[row * 64 + ((ks * 4 + cq) ^ (rr & 7)) * 8];
    }
    #pragma unroll
    for (int n = 0; n < 4; ++n) {
      int row = wn * 64 + n * 16 + rr;
      bf[n] = *(const s16x8*)&LB[row * 64 + ((ks * 4 + cq) ^ (rr & 7)) * 8];
    }
    #pragma unroll
    for (int m = 0; m < 4; ++m)
      #pragma unroll
      for (int n = 0; n < 4; ++n)
        acc[m][n] = __builtin_amdgcn_mfma_f32_16x16x32_bf16(af[m], bf[n], acc[m][n], 0, 0, 0);
  }
}

// ---------------- GEMM1 FUSED: part[kc,b,d,e] = sum_n elu1(K[n,d]) * V[n,e] ----------------
// v6: kc=4 (grid 1024, 4 blocks/CU) to hide the per-iteration latency chain via block-level
// interleave; XCD key = e so the 8 dl-blocks sharing a V-slab land on one XCD's L2.
// LDS layout / barriers / numerics identical to the verified v5.
__global__ __launch_bounds__(256, 2) void k_gemm1f(const float* __restrict__ K, const float* __restrict__ V,
                                                   float* __restrict__ part, float* __restrict__ kspart) {
  __shared__ unsigned short LA[8192], LB[8192];  // 128 rows x 64 shorts each, single-buffered
  int bid = blockIdx.x;                          // (((kc*4+b)*8 + dl)*8 + e)
  int e = bid & 7, dl = (bid >> 3) & 7, cb = bid >> 6;
  int b = cb & 3, kc = cb >> 2;
  int d0 = dl * 128, e0 = e * 128;
  const float* Ksrc = K + ((size_t)b * N_ + kc * 1024) * D_ + d0;
  const float* Vsrc = V + ((size_t)b * N_ + kc * 1024) * D_ + e0;
  int t = threadIdx.x, lane = t & 63, wid = t >> 6, wm = wid >> 1, wn = wid & 1;
  int q = t & 7, dg = t >> 3;                  // n-chunk (8 n), d-group (4 d)
  f32x4 acc[4][4] = {};
  float ks0 = 0.f, ks1 = 0.f, ks2 = 0.f, ks3 = 0.f;
  f32x4 xa[8], xb[8];
  // prologue: loads for tile 0
  #pragma unroll
  for (int j = 0; j < 8; ++j) xa[j] = *(const f32x4*)(Ksrc + (size_t)(q * 8 + j) * D_ + dg * 4);
  #pragma unroll
  for (int j = 0; j < 8; ++j) xb[j] = *(const f32x4*)(Vsrc + (size_t)(q * 8 + j) * D_ + dg * 4);
  for (int it = 0; it < 16; ++it) {
    // convert current regs -> LDS (compiler inserts the vmcnt waits on xa/xb use)
    #pragma unroll
    for (int j = 0; j < 8; ++j) {
      #pragma unroll
      for (int dd = 0; dd < 4; ++dd) xa[j][dd] = elu1f(xa[j][dd]);
    }
    if (e == 0) {
      #pragma unroll
      for (int j = 0; j < 8; ++j) {
        ks0 += xa[j][0]; ks1 += xa[j][1]; ks2 += xa[j][2]; ks3 += xa[j][3];
      }
    }
    #pragma unroll
    for (int dd = 0; dd < 4; ++dd) {
      u32x4 wa, wb;
      #pragma unroll
      for (int c = 0; c < 4; ++c) {
        wa[c] = pack_bf2(xa[2 * c][dd], xa[2 * c + 1][dd]);
        wb[c] = pack_bf2(xb[2 * c][dd], xb[2 * c + 1][dd]);
      }
      int d = dg * 4 + dd;
      int swz = (q ^ (d & 7)) * 8;
      *(u32x4*)&LA[d * 64 + swz] = wa;
      *(u32x4*)&LB[d * 64 + swz] = wb;
    }
    if (it < 15) {                             // next-tile loads: stay in flight across barriers
      #pragma unroll
      for (int j = 0; j < 8; ++j)
        xa[j] = *(const f32x4*)(Ksrc + (size_t)((it + 1) * 64 + q * 8 + j) * D_ + dg * 4);
      #pragma unroll
      for (int j = 0; j < 8; ++j)
        xb[j] = *(const f32x4*)(Vsrc + (size_t)((it + 1) * 64 + q * 8 + j) * D_ + dg * 4);
    }
    asm volatile("s_waitcnt lgkmcnt(0)" ::: "memory");   // own ds_writes visible; vmcnt untouched
    __builtin_amdgcn_s_barrier();                        // tile ready for all waves
    mac128(LA, LB, lane, wm, wn, acc);
    asm volatile("s_waitcnt lgkmcnt(0)" ::: "memory");   // own ds_reads done; fence compiler
    __builtin_amdgcn_s_barrier();                        // safe to overwrite next iteration
  }
  float* P = part + ((size_t)cb << 20) + (size_t)d0 * D_ + e0;
  int rq = (lane >> 4) * 4, cc = lane & 15;
  #pragma unroll
  for (int m = 0; m < 4; ++m)
    #pragma unroll
    for (int r = 0; r < 4; ++r) {
      int row = wm * 64 + m * 16 + rq + r;
      #pragma unroll
      for (int n = 0; n < 4; ++n)
        P[(size_t)row * D_ + wn * 64 + n * 16 + cc] = acc[m][n][r];
    }
  if (e == 0) {                                // ksum partial (fp32, pre-round) for this d-slab
    ks0 += __shfl_xor(ks0, 1, 64); ks0 += __shfl_xor(ks0, 2, 64); ks0 += __shfl_xor(ks0, 4, 64);
    ks1 += __shfl_xor(ks1, 1, 64); ks1 += __shfl_xor(ks1, 2, 64); ks1 += __shfl_xor(ks1, 4, 64);
    ks2 += __shfl_xor(ks2, 1, 64); ks2 += __shfl_xor(ks2, 2, 64); ks2 += __shfl_xor(ks2, 4, 64);
    ks3 += __shfl_xor(ks3, 1, 64); ks3 += __shfl_xor(ks3, 2, 64); ks3 += __shfl_xor(ks3, 4, 64);
    if (q == 0) {
      float* kp = kspart + (size_t)cb * 1024 + d0 + dg * 4;
      kp[0] = ks0; kp[1] = ks1; kp[2] = ks2; kp[3] = ks3;
    }
  }
}

// ---------------- reduce: kvT[b,e,d] = bf16(sum of 4 partials), transposed via LDS ----------------
__global__ __launch_bounds__(256) void k_reduce(const float* __restrict__ part,
                                                unsigned short* __restrict__ kvT) {
  __shared__ unsigned T[64 * 36];              // [e][36] dwords: 32 d-pair dwords + 4 pad
  int bid = blockIdx.x;                        // b(4) x eb(16) x db(16)
  int b = bid >> 8, eb = (bid >> 4) & 15, db = bid & 15;
  const float* p0 = part + ((size_t)b << 20)        + (size_t)(db * 64) * D_ + eb * 64;
  const float* p1 = part + ((size_t)(4 + b) << 20)  + (size_t)(db * 64) * D_ + eb * 64;
  const float* p2 = part + ((size_t)(8 + b) << 20)  + (size_t)(db * 64) * D_ + eb * 64;
  const float* p3 = part + ((size_t)(12 + b) << 20) + (size_t)(db * 64) * D_ + eb * 64;
  int t = threadIdx.x;
  int d0 = (t >> 4) * 4, ec = (t & 15) * 4;    // wave reads 256B/row
  f32x4 a0, a1, a2, a3;
  #pragma unroll
  for (int r = 0; r < 4; ++r) {
    size_t o = (size_t)(d0 + r) * D_ + ec;
    f32x4 s = *(const f32x4*)(p0 + o) + *(const f32x4*)(p1 + o) +
              *(const f32x4*)(p2 + o) + *(const f32x4*)(p3 + o);
    if (r == 0) a0 = s; else if (r == 1) a1 = s; else if (r == 2) a2 = s; else a3 = s;
  }
  #pragma unroll
  for (int j = 0; j < 4; ++j) {
    unsigned lo = (unsigned)f2bf(a0[j]) | ((unsigned)f2bf(a1[j]) << 16);
    unsigned hi = (unsigned)f2bf(a2[j]) | ((unsigned)f2bf(a3[j]) << 16);
    *(unsigned long long*)&T[(ec + j) * 36 + d0 / 2] =
        (unsigned long long)lo | ((unsigned long long)hi << 32);
  }
  __syncthreads();
  int e = t >> 2, cc = t & 3;
  unsigned short* dstb = kvT + ((size_t)b * D_ + eb * 64 + e) * D_ + db * 64;
  #pragma unroll
  for (int m = 0; m < 2; ++m) {
    s16x8 w = *(const s16x8*)&T[e * 36 + cc * 8 + m * 4];
    *(s16x8*)(dstb + cc * 16 + m * 8) = w;
  }
}

// ---------------- GEMM2: out[b,n,e] = (sum_d q'[n,d] kvT[e,d]) / (den+eps) ----------------
__global__ __launch_bounds__(256, 2) void k_gemm2(const unsigned short* __restrict__ qp,
                                                  const unsigned short* __restrict__ kvT,
                                                  const float* __restrict__ den,
                                                  float* __restrict__ out) {
  __shared__ unsigned short LA[2][8192], LB[2][8192];
  int bid = blockIdx.x;
  int b = (bid & 7) >> 1, mh = bid & 1, sg = bid >> 3;
  int ml = sg & 15, e = sg >> 4;
  int m0 = (mh * 16 + ml) * 128, e0 = e * 128;
  const unsigned short* A  = qp  + ((size_t)b * N_ + m0) * D_;
  const unsigned short* Bp = kvT + ((size_t)b * D_ + e0) * D_;
  int t = threadIdx.x, lane = t & 63, wid = t >> 6, wm = wid >> 1, wn = wid & 1;
  f32x4 acc[4][4] = {};
  stage8(A, Bp, D_, D_, LA[0], LB[0], t, 0);
  asm volatile("s_waitcnt vmcnt(0)" ::: "memory");
  __syncthreads();
  int cur = 0;
  for (int it = 0; it < 16; ++it) {
    if (it < 15) stage8(A, Bp, D_, D_, LA[cur ^ 1], LB[cur ^ 1], t, (it + 1) * 64);
    mac128(LA[cur], LB[cur], lane, wm, wn, acc);
    asm volatile("s_waitcnt vmcnt(0)" ::: "memory");
    __syncthreads();
    cur ^= 1;
  }
  const float* dn = den + b * N_ + m0;
  float* ob = out + ((size_t)b * N_ + m0) * D_ + e0;
  int rq = (lane >> 4) * 4, cc = lane & 15;
  #pragma unroll
  for (int m = 0; m < 4; ++m)
    #pragma unroll
    for (int r = 0; r < 4; ++r) {
      int row = wm * 64 + m * 16 + rq + r;
      float inv = 1.f / (dn[row] + 1e-6f);
      #pragma unroll
      for (int n = 0; n < 4; ++n)
        ob[(size_t)row * D_ + wn * 64 + n * 16 + cc] = acc[m][n][r] * inv;
    }
}

extern "C" void kernel_launch(void* const* d_in, const int* in_sizes, int n_in,
                              void* d_out, int out_size, void* d_ws, size_t ws_size,
                              hipStream_t stream) {
  const float* q = (const float*)d_in[0];
  const float* k = (const float*)d_in[1];
  const float* v = (const float*)d_in[2];
  float* outF = (float*)d_out;
  char* ws = (char*)d_ws;

  // ws: qp 32MB | kvT 8MB | ksum 16KB | den 64KB | kspart 64KB  (= 40.1MB)
  unsigned short* qp  = (unsigned short*)ws;
  unsigned short* kvT = (unsigned short*)(ws + ((size_t)32 << 20));
  float* ksum   = (float*)(ws + ((size_t)40 << 20));
  float* den    = (float*)(ws + ((size_t)40 << 20) + 16384);
  float* kspart = (float*)(ws + ((size_t)40 << 20) + 16384 + 65536);
  // d_out doubles as scratch (fully overwritten by k_gemm2 afterwards):
  float* part = outF;                  // 16 x 4MB fp32 kv partials (= 64MB, fills d_out)

  k_gemm1f<<<1024, 256, 0, stream>>>(k, v, part, kspart);
  k_prep_q<<<1024, 256, 0, stream>>>(q, qp);
  k_ksum2 <<<16, 256, 0, stream>>>(kspart, ksum);
  k_reduce<<<1024, 256, 0, stream>>>(part, kvT);
  k_denom <<<4096, 256, 0, stream>>>(qp, ksum, den);
  k_gemm2 <<<1024, 256, 0, stream>>>(qp, kvT, den, outF);
}

// Round 7
// 168.001 us; speedup vs baseline: 1.3369x; 1.3369x over previous
//
#include <hip/hip_runtime.h>

#define DEV __device__ __forceinline__

typedef __attribute__((ext_vector_type(4))) float f32x4;
typedef __attribute__((ext_vector_type(8))) short s16x8;

constexpr int B_ = 4, N_ = 4096, D_ = 1024;

DEV float elu1f(float x) { return x > 0.f ? x + 1.f : __expf(x); }
DEV unsigned short f2bf(float x) {            // RNE fp32 -> bf16
  unsigned u = __float_as_uint(x);
  return (unsigned short)((u + 0x7fffu + ((u >> 16) & 1u)) >> 16);
}
DEV float bf2f(unsigned short h) { return __uint_as_float(((unsigned)h) << 16); }

// ---------------- prep: K,V elu+transpose (v1 verbatim) + q elu->bf16 stream ----------------
// bid < 8192: z(2) * b(4) * nb(64) * db(16) transpose blocks (v1 k_prep_tr, 64n x 64d tile).
// bid >= 8192: 1024 grid-stride blocks doing v1 k_prep_q. Pure-stream blocks fill the
// latency bubbles of the transpose blocks co-resident on the same CUs.
__global__ __launch_bounds__(256) void k_prep(const float* __restrict__ Q, const float* __restrict__ K,
                                              const float* __restrict__ V,
                                              unsigned short* __restrict__ qp, unsigned short* __restrict__ kT,
                                              unsigned short* __restrict__ vT, float* __restrict__ kspart) {
  __shared__ unsigned short T[64 * 68];        // [n][d] tile, stride 68
  int bid = blockIdx.x;
  if (bid >= 8192) {                           // ---- q-stream path (v1 k_prep_q) ----
    int n = B_ * N_ * D_ / 4;
    int stride = 1024 * 256;
    for (int i = (bid - 8192) * 256 + threadIdx.x; i < n; i += stride) {
      f32x4 x = ((const f32x4*)Q)[i];
      unsigned long long r =
          (unsigned long long)((unsigned)f2bf(elu1f(x[0])) | ((unsigned)f2bf(elu1f(x[1])) << 16)) |
          ((unsigned long long)((unsigned)f2bf(elu1f(x[2])) | ((unsigned)f2bf(elu1f(x[3])) << 16)) << 32);
      ((unsigned long long*)qp)[i] = r;
    }
    return;
  }
  // ---- transpose path (v1 k_prep_tr verbatim) ----
  int z = bid >> 12;
  int r = bid & 4095;
  int b = r >> 10, nb = (r >> 4) & 63, db = r & 15;
  const float* src = (z ? V : K) + ((size_t)b * N_ + nb * 64) * D_ + db * 64;
  unsigned short* dst = (z ? vT : kT) + ((size_t)b * D_ + db * 64) * N_ + nb * 64;
  int t = threadIdx.x;
  int nr = t >> 4, dc = (t & 15) * 4;
  #pragma unroll
  for (int u = 0; u < 4; ++u) {
    int n = nr + u * 16;
    f32x4 x = *(const f32x4*)(src + (size_t)n * D_ + dc);
    if (z == 0) { x[0] = elu1f(x[0]); x[1] = elu1f(x[1]); x[2] = elu1f(x[2]); x[3] = elu1f(x[3]); }
    unsigned long long pk =
        (unsigned long long)((unsigned)f2bf(x[0]) | ((unsigned)f2bf(x[1]) << 16)) |
        ((unsigned long long)((unsigned)f2bf(x[2]) | ((unsigned)f2bf(x[3]) << 16)) << 32);
    *(unsigned long long*)&T[n * 68 + dc] = pk;
  }
  __syncthreads();
  int d = t >> 2, c = (t & 3) * 16;            // output row d (64), n-chunk c (4x16)
  unsigned short tmp[16];
  float s = 0.f;
  #pragma unroll
  for (int j = 0; j < 16; ++j) { unsigned short h = T[(c + j) * 68 + d]; tmp[j] = h; s += bf2f(h); }
  *(s16x8*)(dst + (size_t)d * N_ + c) = *(s16x8*)&tmp[0];
  *(s16x8*)(dst + (size_t)d * N_ + c + 8) = *(s16x8*)&tmp[8];
  if (z == 0) {                                 // fused ksum partial over this block's 64 n
    s += __shfl_xor(s, 1, 64);
    s += __shfl_xor(s, 2, 64);
    if ((t & 3) == 0) kspart[((size_t)b * 64 + nb) * D_ + db * 64 + d] = s;
  }
}

// ---------------- shared GEMM machinery: 128x128 tile, BK=64, glds + XOR swizzle ----------------
DEV void stage8(const unsigned short* __restrict__ A, const unsigned short* __restrict__ Bp,
                long sA, long sB, unsigned short* LA, unsigned short* LB, int t, int kofs) {
  #pragma unroll
  for (int j = 0; j < 4; ++j) {
    int q = j * 256 + t;
    int r = q >> 3;
    int c = (q & 7) ^ (r & 7);
    const unsigned short* g = A + (size_t)r * sA + kofs + c * 8;
    unsigned short* l = LA + (q & ~63) * 8;    // wave-uniform base; HW adds lane*16
    __builtin_amdgcn_global_load_lds((const __attribute__((address_space(1))) unsigned int*)(const void*)g,
                                     (__attribute__((address_space(3))) unsigned int*)(void*)l, 16, 0, 0);
  }
  #pragma unroll
  for (int j = 0; j < 4; ++j) {
    int q = j * 256 + t;
    int r = q >> 3;
    int c = (q & 7) ^ (r & 7);
    const unsigned short* g = Bp + (size_t)r * sB + kofs + c * 8;
    unsigned short* l = LB + (q & ~63) * 8;
    __builtin_amdgcn_global_load_lds((const __attribute__((address_space(1))) unsigned int*)(const void*)g,
                                     (__attribute__((address_space(3))) unsigned int*)(void*)l, 16, 0, 0);
  }
}

DEV void mac128(const unsigned short* LA, const unsigned short* LB, int lane, int wm, int wn,
                f32x4 (&acc)[4][4]) {
  int rr = lane & 15, cq = lane >> 4;
  #pragma unroll
  for (int ks = 0; ks < 2; ++ks) {
    s16x8 af[4], bf[4];
    #pragma unroll
    for (int m = 0; m < 4; ++m) {
      int row = wm * 64 + m * 16 + rr;
      af[m] = *(const s16x8*)&LA[row * 64 + ((ks * 4 + cq) ^ (rr & 7)) * 8];
    }
    #pragma unroll
    for (int n = 0; n < 4; ++n) {
      int row = wn * 64 + n * 16 + rr;
      bf[n] = *(const s16x8*)&LB[row * 64 + ((ks * 4 + cq) ^ (rr & 7)) * 8];
    }
    #pragma unroll
    for (int m = 0; m < 4; ++m)
      #pragma unroll
      for (int n = 0; n < 4; ++n)
        acc[m][n] = __builtin_amdgcn_mfma_f32_16x16x32_bf16(af[m], bf[n], acc[m][n], 0, 0, 0);
  }
}

// ---------------- GEMM1 (v1 verbatim) + ksum2 tail blocks ----------------
// bid < 512: part[kc,b,d,e] = sum_{n in kc-half} k'T[d,n] vT[e,n], fp32.
// bid >= 512 (16 blocks): ksum[b,d] = sum of 64 kspart partials (v1 k_ksum2).
__global__ __launch_bounds__(256, 2) void k_g1(const unsigned short* __restrict__ kT,
                                               const unsigned short* __restrict__ vT,
                                               float* __restrict__ part,
                                               const float* __restrict__ kspart,
                                               float* __restrict__ ksum) {
  __shared__ unsigned short LA[2][8192], LB[2][8192];
  int bid = blockIdx.x;
  if (bid >= 512) {                            // ---- ksum2 path ----
    int idx = (bid - 512) * 256 + threadIdx.x; // 4096 = b*1024 + d
    int b = idx >> 10, d = idx & 1023;
    float a = 0.f;
    #pragma unroll 8
    for (int s = 0; s < 64; ++s) a += kspart[((size_t)b * 64 + s) * D_ + d];
    ksum[idx] = a;
    return;
  }
  int b = (bid & 7) >> 1, dh = bid & 1, sg = bid >> 3;
  int kc = sg & 1, dl = (sg >> 1) & 3, e = sg >> 3;
  int d0 = (dh * 4 + dl) * 128, e0 = e * 128;
  const unsigned short* A  = kT + ((size_t)b * D_ + d0) * N_ + kc * 2048;
  const unsigned short* Bp = vT + ((size_t)b * D_ + e0) * N_ + kc * 2048;
  int t = threadIdx.x, lane = t & 63, wid = t >> 6, wm = wid >> 1, wn = wid & 1;
  f32x4 acc[4][4] = {};
  stage8(A, Bp, N_, N_, LA[0], LB[0], t, 0);
  asm volatile("s_waitcnt vmcnt(0)" ::: "memory");
  __syncthreads();
  int cur = 0;
  for (int it = 0; it < 32; ++it) {
    if (it < 31) stage8(A, Bp, N_, N_, LA[cur ^ 1], LB[cur ^ 1], t, (it + 1) * 64);
    mac128(LA[cur], LB[cur], lane, wm, wn, acc);
    asm volatile("s_waitcnt vmcnt(0)" ::: "memory");
    __syncthreads();
    cur ^= 1;
  }
  float* P = part + ((size_t)(kc * 4 + b) << 20) + (size_t)d0 * D_ + e0;
  int rq = (lane >> 4) * 4, cc = lane & 15;
  #pragma unroll
  for (int m = 0; m < 4; ++m)
    #pragma unroll
    for (int r = 0; r < 4; ++r) {
      int row = wm * 64 + m * 16 + rq + r;
      #pragma unroll
      for (int n = 0; n < 4; ++n)
        P[(size_t)row * D_ + wn * 64 + n * 16 + cc] = acc[m][n][r];
    }
}

// ---------------- reduce (v1 verbatim) + denom tail blocks ----------------
// bid < 1024: kvT[b,e,d] = bf16(part0+part1), transposed via LDS.
// bid >= 1024 (4096 blocks): den[b,n] = sum_d q'_bf16 * ksum (v1 k_denom).
__global__ __launch_bounds__(256) void k_rd(const float* __restrict__ part,
                                            unsigned short* __restrict__ kvT,
                                            const unsigned short* __restrict__ qp,
                                            const float* __restrict__ ksum,
                                            float* __restrict__ den) {
  __shared__ unsigned T[64 * 36];              // [e][36] dwords: 32 d-pair dwords + 4 pad
  int bid = blockIdx.x;
  if (bid >= 1024) {                           // ---- denom path ----
    int wid = threadIdx.x >> 6, lane = threadIdx.x & 63;
    int row = (bid - 1024) * 4 + wid;          // [0, B*N)
    int b = row >> 12;
    const unsigned short* qr = qp + (size_t)row * D_ + lane * 16;
    const float* ks = ksum + b * D_ + lane * 16;
    s16x8 h0 = *(const s16x8*)qr;
    s16x8 h1 = *(const s16x8*)(qr + 8);
    float acc = 0.f;
    #pragma unroll
    for (int j = 0; j < 8; ++j) acc += bf2f((unsigned short)h0[j]) * ks[j];
    #pragma unroll
    for (int j = 0; j < 8; ++j) acc += bf2f((unsigned short)h1[j]) * ks[8 + j];
    #pragma unroll
    for (int o = 32; o; o >>= 1) acc += __shfl_down(acc, o, 64);
    if (!lane) den[row] = acc;
    return;
  }
  // ---- reduce path (v1 k_reduce, dword-pair LDS transpose) ----
  int b = bid >> 8, eb = (bid >> 4) & 15, db = bid & 15;
  const float* p0 = part + ((size_t)b << 20) + (size_t)(db * 64) * D_ + eb * 64;
  const float* p1 = p0 + ((size_t)4 << 20);
  int t = threadIdx.x;
  int d0 = (t >> 4) * 4, ec = (t & 15) * 4;    // wave reads 256B/row
  f32x4 a0 = *(const f32x4*)(p0 + (size_t)d0 * D_ + ec)       + *(const f32x4*)(p1 + (size_t)d0 * D_ + ec);
  f32x4 a1 = *(const f32x4*)(p0 + (size_t)(d0 + 1) * D_ + ec) + *(const f32x4*)(p1 + (size_t)(d0 + 1) * D_ + ec);
  f32x4 a2 = *(const f32x4*)(p0 + (size_t)(d0 + 2) * D_ + ec) + *(const f32x4*)(p1 + (size_t)(d0 + 2) * D_ + ec);
  f32x4 a3 = *(const f32x4*)(p0 + (size_t)(d0 + 3) * D_ + ec) + *(const f32x4*)(p1 + (size_t)(d0 + 3) * D_ + ec);
  #pragma unroll
  for (int j = 0; j < 4; ++j) {
    unsigned lo = (unsigned)f2bf(a0[j]) | ((unsigned)f2bf(a1[j]) << 16);
    unsigned hi = (unsigned)f2bf(a2[j]) | ((unsigned)f2bf(a3[j]) << 16);
    *(unsigned long long*)&T[(ec + j) * 36 + d0 / 2] =
        (unsigned long long)lo | ((unsigned long long)hi << 32);
  }
  __syncthreads();
  int e = t >> 2, cc = t & 3;
  unsigned short* dstb = kvT + ((size_t)b * D_ + eb * 64 + e) * D_ + db * 64;
  #pragma unroll
  for (int m = 0; m < 2; ++m) {
    s16x8 w = *(const s16x8*)&T[e * 36 + cc * 8 + m * 4];
    *(s16x8*)(dstb + cc * 16 + m * 8) = w;
  }
}

// ---------------- GEMM2 (v1 verbatim): out[b,n,e] = (sum_d q'[n,d] kvT[e,d]) / (den+eps) ----------------
__global__ __launch_bounds__(256, 2) void k_gemm2(const unsigned short* __restrict__ qp,
                                                  const unsigned short* __restrict__ kvT,
                                                  const float* __restrict__ den,
                                                  float* __restrict__ out) {
  __shared__ unsigned short LA[2][8192], LB[2][8192];
  int bid = blockIdx.x;
  int b = (bid & 7) >> 1, mh = bid & 1, sg = bid >> 3;
  int ml = sg & 15, e = sg >> 4;
  int m0 = (mh * 16 + ml) * 128, e0 = e * 128;
  const unsigned short* A  = qp  + ((size_t)b * N_ + m0) * D_;
  const unsigned short* Bp = kvT + ((size_t)b * D_ + e0) * D_;
  int t = threadIdx.x, lane = t & 63, wid = t >> 6, wm = wid >> 1, wn = wid & 1;
  f32x4 acc[4][4] = {};
  stage8(A, Bp, D_, D_, LA[0], LB[0], t, 0);
  asm volatile("s_waitcnt vmcnt(0)" ::: "memory");
  __syncthreads();
  int cur = 0;
  for (int it = 0; it < 16; ++it) {
    if (it < 15) stage8(A, Bp, D_, D_, LA[cur ^ 1], LB[cur ^ 1], t, (it + 1) * 64);
    mac128(LA[cur], LB[cur], lane, wm, wn, acc);
    asm volatile("s_waitcnt vmcnt(0)" ::: "memory");
    __syncthreads();
    cur ^= 1;
  }
  const float* dn = den + b * N_ + m0;
  float* ob = out + ((size_t)b * N_ + m0) * D_ + e0;
  int rq = (lane >> 4) * 4, cc = lane & 15;
  #pragma unroll
  for (int m = 0; m < 4; ++m)
    #pragma unroll
    for (int r = 0; r < 4; ++r) {
      int row = wm * 64 + m * 16 + rq + r;
      float inv = 1.f / (dn[row] + 1e-6f);
      #pragma unroll
      for (int n = 0; n < 4; ++n)
        ob[(size_t)row * D_ + wn * 64 + n * 16 + cc] = acc[m][n][r] * inv;
    }
}

extern "C" void kernel_launch(void* const* d_in, const int* in_sizes, int n_in,
                              void* d_out, int out_size, void* d_ws, size_t ws_size,
                              hipStream_t stream) {
  const float* q = (const float*)d_in[0];
  const float* k = (const float*)d_in[1];
  const float* v = (const float*)d_in[2];
  float* outF = (float*)d_out;
  char* ws = (char*)d_ws;

  // ws: qp 32MB | kT 32MB | vT 32MB | kvT 8MB | ksum 16KB | den 64KB  (= 104.1MB)
  unsigned short* qp  = (unsigned short*)ws;
  unsigned short* kT  = (unsigned short*)(ws + ((size_t)32 << 20));
  unsigned short* vT  = (unsigned short*)(ws + ((size_t)64 << 20));
  unsigned short* kvT = (unsigned short*)(ws + ((size_t)96 << 20));
  float* ksum = (float*)(ws + ((size_t)104 << 20));
  float* den  = (float*)(ws + ((size_t)104 << 20) + 16384);
  // d_out doubles as scratch (fully overwritten by k_gemm2 afterwards):
  float* part   = outF;                 // 2 x 16MB fp32 kv partials
  float* kspart = outF + (8 << 20);     // 1MB ksum partials at +32MB

  k_prep <<<9216, 256, 0, stream>>>(q, k, v, qp, kT, vT, kspart);
  k_g1   <<<528, 256, 0, stream>>>(kT, vT, part, kspart, ksum);
  k_rd   <<<5120, 256, 0, stream>>>(part, kvT, qp, ksum, den);
  k_gemm2<<<1024, 256, 0, stream>>>(qp, kvT, den, outF);
}